// Round 7
// baseline (675.573 us; speedup 1.0000x reference)
//
#include <hip/hip_runtime.h>
#include <math.h>
#include <float.h>

#define NN 100000
#define NE 1600000
#define ETOT 1700000   // NE + NN self loops
#define DIN 264
#define DH 64
#define SLOPE 0.2f
#define NB 98          // scan blocks: ceil(NN/1024)
#define NSHARD 8       // one dst-range shard per XCD
#define SHW 12500      // NN / NSHARD
#define EPB 2048       // edges per block-chunk in sharded edge kernels

typedef __attribute__((ext_vector_type(8))) short s8v;   // 8 bf16 = 4 VGPR
typedef __attribute__((ext_vector_type(4))) float f4v;   // MFMA acc

__device__ __forceinline__ unsigned short f2bf(float x) {  // rne f32->bf16
  unsigned u = __float_as_uint(x);
  u += 0x7FFFu + ((u >> 16) & 1u);
  return (unsigned short)(u >> 16);
}
__device__ __forceinline__ float bf2f(unsigned short h) {
  return __uint_as_float(((unsigned)h) << 16);
}

__global__ void k_mean(const float* __restrict__ ea, float* __restrict__ sum) {
  float acc = 0.f;
  for (int i = blockIdx.x * blockDim.x + threadIdx.x; i < NE; i += gridDim.x * blockDim.x)
    acc += ea[i];
  #pragma unroll
  for (int off = 32; off > 0; off >>= 1) acc += __shfl_xor(acc, off);
  __shared__ float s[4];
  int lane = threadIdx.x & 63, w = threadIdx.x >> 6;
  if (lane == 0) s[w] = acc;
  __syncthreads();
  if (threadIdx.x == 0) atomicAdd(sum, s[0] + s[1] + s[2] + s[3]);
}

// XCD-sharded histogram: blocks with blockIdx%8==b own dst range
// [b*SHW,(b+1)*SHW).  Round-robin block->XCD dispatch (perf heuristic,
// correctness shard-exhaustive) keeps each deg/csr line dirty on ONE XCD.
__global__ __launch_bounds__(256)
void k_hist(const int* __restrict__ ei, unsigned* __restrict__ deg) {
  const int shard = blockIdx.x & (NSHARD - 1);
  const int g = blockIdx.x >> 3;
  const int dlo = shard * SHW, dhi = dlo + SHW;
  int e0 = g * EPB + threadIdx.x;
  #pragma unroll
  for (int k = 0; k < EPB / 256; k++) {
    int e = e0 + k * 256;
    if (e < ETOT) {
      int d = (e < NE) ? ei[NE + e] : e - NE;
      if (d >= dlo && d < dhi) atomicAdd(&deg[d], 1u);
    }
  }
}

// ---- parallel 3-phase scan ----
__global__ __launch_bounds__(256)
void k_bsum(const unsigned* __restrict__ deg, unsigned* __restrict__ bsum) {
  int i0 = blockIdx.x * 1024 + threadIdx.x * 4;
  unsigned s = 0;
  if (i0 + 3 < NN) {
    uint4 v = *(const uint4*)&deg[i0];
    s = v.x + v.y + v.z + v.w;
  }
  #pragma unroll
  for (int off = 32; off > 0; off >>= 1) s += __shfl_xor(s, off);
  __shared__ unsigned ws[4];
  int lane = threadIdx.x & 63, w = threadIdx.x >> 6;
  if (lane == 0) ws[w] = s;
  __syncthreads();
  if (threadIdx.x == 0) bsum[blockIdx.x] = ws[0] + ws[1] + ws[2] + ws[3];
}

__global__ __launch_bounds__(128)
void k_sscan(unsigned* __restrict__ bsum, unsigned* __restrict__ rowptr) {
  __shared__ unsigned ls[128];
  int t = threadIdx.x;
  unsigned v = (t < NB) ? bsum[t] : 0u;
  ls[t] = v;
  __syncthreads();
  for (int off = 1; off < 128; off <<= 1) {
    unsigned u = (t >= off) ? ls[t - off] : 0u;
    __syncthreads();
    ls[t] += u;
    __syncthreads();
  }
  if (t < NB) bsum[t] = ls[t] - v;  // exclusive
  if (t == 127) rowptr[NN] = ls[127];
}

__global__ __launch_bounds__(256)
void k_scan2(const unsigned* __restrict__ deg, const unsigned* __restrict__ bsum,
             unsigned* __restrict__ rowptr, unsigned* __restrict__ wptr) {
  __shared__ unsigned ls[256];
  int i0 = blockIdx.x * 1024 + threadIdx.x * 4;
  unsigned d0 = 0, d1 = 0, d2 = 0, d3 = 0;
  if (i0 + 3 < NN) {
    uint4 v = *(const uint4*)&deg[i0];
    d0 = v.x; d1 = v.y; d2 = v.z; d3 = v.w;
  }
  unsigned ts = d0 + d1 + d2 + d3;
  ls[threadIdx.x] = ts;
  __syncthreads();
  for (int off = 1; off < 256; off <<= 1) {
    unsigned u = (threadIdx.x >= (unsigned)off) ? ls[threadIdx.x - off] : 0u;
    __syncthreads();
    ls[threadIdx.x] += u;
    __syncthreads();
  }
  unsigned base = bsum[blockIdx.x] + ls[threadIdx.x] - ts;  // exclusive
  if (i0 + 3 < NN) {
    uint4 r;
    r.x = base;
    r.y = base + d0;
    r.z = r.y + d1;
    r.w = r.z + d2;
    *(uint4*)&rowptr[i0] = r;
    *(uint4*)&wptr[i0] = r;
  }
}

// XCD-sharded CSR scatter (see k_hist comment).
__global__ __launch_bounds__(256)
void k_scatter(const int* __restrict__ ei, const float* __restrict__ ea,
               const float* __restrict__ sump, unsigned* __restrict__ wptr,
               int2* __restrict__ csr) {
  const int shard = blockIdx.x & (NSHARD - 1);
  const int g = blockIdx.x >> 3;
  const int dlo = shard * SHW, dhi = dlo + SHW;
  int e0 = g * EPB + threadIdx.x;
  #pragma unroll
  for (int k = 0; k < EPB / 256; k++) {
    int e = e0 + k * 256;
    if (e >= ETOT) continue;
    int d = (e < NE) ? ei[NE + e] : e - NE;
    if (d < dlo || d >= dhi) continue;
    int s;
    float a;
    if (e < NE) {
      s = ei[e];
      a = ea[e];
    } else {
      s = d;
      a = sump[0] * (1.0f / NE);
    }
    unsigned pos = atomicAdd(&wptr[d], 1u);
    csr[pos] = make_int2(s, __float_as_int(a));
  }
}

// Repack Wl|Wr (K x 64 row-major fp32) into MFMA B-fragment order, split
// bf16 hi/lo.  8 n-tiles total (0-3 -> Wl, 4-7 -> Wr); per fragment, lane l
// supplies B[k = kc*32 + 8*(l>>4) + i][n = nt*16 + (l&15)] (zero-pad k >= K).
template <int K>
__global__ __launch_bounds__(256)
void k_wprep(const float* __restrict__ Wl, const float* __restrict__ Wr,
             unsigned short* __restrict__ wfh, unsigned short* __restrict__ wfl) {
  constexpr int KC = (K + 31) / 32;
  int t = blockIdx.x * blockDim.x + threadIdx.x;  // one thread per fragment-lane
  if (t >= 8 * KC * 64) return;
  int lane = t & 63;
  int kc = (t >> 6) % KC;
  int ntg = t / (64 * KC);
  const float* src = (ntg < 4) ? Wl : Wr;
  int n = (ntg & 3) * 16 + (lane & 15);
  int k0 = kc * 32 + (lane >> 4) * 8;
  #pragma unroll
  for (int i = 0; i < 8; i++) {
    int k = k0 + i;
    float v = (k < K) ? src[k * DH + n] : 0.f;
    unsigned short hh = f2bf(v);
    wfh[t * 8 + i] = hh;
    wfl[t * 8 + i] = f2bf(v - bf2f(hh));
  }
}

// MFMA GEMM: [xl xr] = X @ [Wl Wr] + [bl br] via split-bf16
// (Xh*Wh + Xh*Wlo + Xlo*Wh; dropped lo*lo term <= 2^-16 relative).
// 512 threads = 8 waves per 64-row block; wave w owns ONE n-tile
// (w<4 -> xl cols, w>=4 -> xr cols), all 4 m-tiles.  Wave's ENTIRE B set
// preloaded to registers before staging; K-loop is LDS+MFMA only.
template <int K>
__global__ __launch_bounds__(512) __attribute__((amdgpu_waves_per_eu(4)))
void k_mm(const float* __restrict__ X,
          const unsigned short* __restrict__ wfh, const unsigned short* __restrict__ wfl,
          const float* __restrict__ bl, const float* __restrict__ br,
          float* __restrict__ xl, float* __restrict__ xr) {
  constexpr int KC = (K + 31) / 32;
  constexpr int KP = KC * 32;
  constexpr int SP = KP + 8;  // +8 shorts: bank-spread for the A-frag reads
  __shared__ unsigned short lsh[64 * SP];
  __shared__ unsigned short lsl[64 * SP];
  const int r0 = blockIdx.x * 64;
  const int tid = threadIdx.x;
  const int lane = tid & 63, w = tid >> 6;
  const int kq = lane >> 4;   // k-octet / C-row group
  const int ar = lane & 15;   // A row within tile / C col

  // ---- preload this wave's B fragments (n-tile = w) for all kc ----
  s8v bh[KC], bv[KC];
  #pragma unroll
  for (int kc = 0; kc < KC; kc++) {
    const int bidx = ((w * KC + kc) * 64 + lane) * 8;
    bh[kc] = *(const s8v*)&wfh[bidx];
    bv[kc] = *(const s8v*)&wfl[bidx];
  }

  // ---- stage X -> LDS bf16 hi/lo (coalesced float2 loads) ----
  if constexpr (KP > K) {  // zero the k-pad strip [K, KP)
    constexpr int PADW = (KP - K) / 2;  // uints per row
    for (int t = tid; t < 64 * PADW; t += 512) {
      int row = t / PADW, c = t - row * PADW;
      *(unsigned*)&lsh[row * SP + K + 2 * c] = 0u;
      *(unsigned*)&lsl[row * SP + K + 2 * c] = 0u;
    }
  }
  {
    constexpr int HK = K / 2;
    for (int p = tid; p < 64 * HK; p += 512) {
      int row = p / HK, kp = p - row * HK;
      int grow = r0 + row;
      float a = 0.f, b = 0.f;
      if (grow < NN) {
        float2 v = *(const float2*)&X[(size_t)grow * K + 2 * kp];
        a = v.x; b = v.y;
      }
      unsigned short ha = f2bf(a), hb = f2bf(b);
      unsigned short la = f2bf(a - bf2f(ha)), lb = f2bf(b - bf2f(hb));
      *(unsigned*)&lsh[row * SP + 2 * kp] = (unsigned)ha | ((unsigned)hb << 16);
      *(unsigned*)&lsl[row * SP + 2 * kp] = (unsigned)la | ((unsigned)lb << 16);
    }
  }
  __syncthreads();

  // ---- K-loop: LDS reads + MFMA only ----
  f4v acc[4];
  #pragma unroll
  for (int mt = 0; mt < 4; mt++) acc[mt] = (f4v){0.f, 0.f, 0.f, 0.f};
  #pragma unroll
  for (int kc = 0; kc < KC; kc++) {
    const int kb = kc * 32 + kq * 8;
    #pragma unroll
    for (int mt = 0; mt < 4; mt++) {
      s8v ah = *(const s8v*)&lsh[(mt * 16 + ar) * SP + kb];
      s8v al = *(const s8v*)&lsl[(mt * 16 + ar) * SP + kb];
      acc[mt] = __builtin_amdgcn_mfma_f32_16x16x32_bf16(ah, bh[kc], acc[mt], 0, 0, 0);
      acc[mt] = __builtin_amdgcn_mfma_f32_16x16x32_bf16(ah, bv[kc], acc[mt], 0, 0, 0);
      acc[mt] = __builtin_amdgcn_mfma_f32_16x16x32_bf16(al, bh[kc], acc[mt], 0, 0, 0);
    }
  }

  // C/D layout (m89-verified): col = lane&15, row = (lane>>4)*4 + reg
  const float* bias = (w < 4) ? bl : br;
  float* outp = (w < 4) ? xl : xr;
  const int col = (w & 3) * 16 + ar;
  const float bvv = bias[col];
  #pragma unroll
  for (int mt = 0; mt < 4; mt++) {
    #pragma unroll
    for (int r = 0; r < 4; r++) {
      int grow = r0 + mt * 16 + kq * 4 + r;
      if (grow < NN) outp[(size_t)grow * DH + col] = acc[mt][r] + bvv;
    }
  }
}

// Fused per-node attention: 16 lanes own one dst node; online softmax + max-aggregate.
// Round-7: (1) single-exp branch update -- when p<=M (common after a few edges)
// sO==exp(0)==1 exactly, so skip the V/D rescale; when p>M, sN==1.  Bit-exact
// vs the two-exp form, saves 1 transcendental + ~6 VALU per edge; branch is
// group-uniform (p,M uniform across the 16 lanes).  (2) 8-deep gather batches
// (2x memory-level parallelism; sl[8]+av[8] ~= 56 VGPR, still under the
// 64-VGPR/8-wave boundary).  (3) csr chunk prefetch (clamped, always in-bounds).
template <bool HEAD>
__global__ void k_attn(const unsigned* __restrict__ rowptr, const int2* __restrict__ csr,
                       const float* __restrict__ xl, const float* __restrict__ xr,
                       const float* __restrict__ We, const float* __restrict__ att,
                       const float* __restrict__ bias, float* __restrict__ h,
                       const float* __restrict__ W3, const float* __restrict__ b3,
                       const float* __restrict__ W4, const float* __restrict__ b4,
                       float* __restrict__ out) {
  int n = (blockIdx.x * blockDim.x + threadIdx.x) >> 4;
  int l = threadIdx.x & 15;
  int g0 = threadIdx.x & 48;  // 16-lane group base within the wave
  if (n >= NN) return;        // exact division: never taken, no partial groups
  int l4 = l * 4;
  float4 xr4 = *(const float4*)&xr[n * DH + l4];
  float4 we4 = *(const float4*)&We[l4];
  float4 at4 = *(const float4*)&att[l4];
  int beg = rowptr[n], end = rowptr[n + 1];  // deg >= 1 (self loop)
  float M, D;
  float4 V;
  {  // peel first edge
    int2 c0 = csr[beg];
    float a = __int_as_float(c0.y);
    float4 sl = *(const float4*)&xl[c0.x * DH + l4];
    float v, p = 0.f;
    v = xr4.x + sl.x + a * we4.x; v = fmaxf(v, SLOPE * v); p += v * at4.x;
    v = xr4.y + sl.y + a * we4.y; v = fmaxf(v, SLOPE * v); p += v * at4.y;
    v = xr4.z + sl.z + a * we4.z; v = fmaxf(v, SLOPE * v); p += v * at4.z;
    v = xr4.w + sl.w + a * we4.w; v = fmaxf(v, SLOPE * v); p += v * at4.w;
    p += __shfl_xor(p, 1);
    p += __shfl_xor(p, 2);
    p += __shfl_xor(p, 4);
    p += __shfl_xor(p, 8);
    M = p; D = 1.f; V = sl;
  }
  int2 cl = csr[min(beg + 1 + l, end - 1)];  // first chunk (clamped, in-bounds)
  for (int e0 = beg + 1; e0 < end; e0 += 16) {
    int2 cln = csr[min(e0 + 16 + l, end - 1)];  // prefetch next chunk
    int cnt = min(16, end - e0);
    for (int i = 0; i < cnt; i += 8) {
      int mm = min(8, cnt - i);
      float4 sl[8];
      float av[8];
      #pragma unroll
      for (int j = 0; j < 8; j++) {
        if (j < mm) {
          int s = __shfl(cl.x, g0 + i + j);
          av[j] = __int_as_float(__shfl(cl.y, g0 + i + j));
          sl[j] = *(const float4*)&xl[s * DH + l4];  // 8 gathers in flight
        }
      }
      #pragma unroll
      for (int j = 0; j < 8; j++) {
        if (j < mm) {
          float a = av[j];
          float v, p = 0.f;
          v = xr4.x + sl[j].x + a * we4.x; v = fmaxf(v, SLOPE * v); p += v * at4.x;
          v = xr4.y + sl[j].y + a * we4.y; v = fmaxf(v, SLOPE * v); p += v * at4.y;
          v = xr4.z + sl[j].z + a * we4.z; v = fmaxf(v, SLOPE * v); p += v * at4.z;
          v = xr4.w + sl[j].w + a * we4.w; v = fmaxf(v, SLOPE * v); p += v * at4.w;
          p += __shfl_xor(p, 1);
          p += __shfl_xor(p, 2);
          p += __shfl_xor(p, 4);
          p += __shfl_xor(p, 8);
          if (p <= M) {  // common: no new max; sO == 1 exactly
            float sN = __expf(p - M);
            D += sN;
            V.x = fmaxf(V.x, sl[j].x * sN);
            V.y = fmaxf(V.y, sl[j].y * sN);
            V.z = fmaxf(V.z, sl[j].z * sN);
            V.w = fmaxf(V.w, sl[j].w * sN);
          } else {       // new max; sN == 1 exactly
            float sO = __expf(M - p);
            D = fmaf(D, sO, 1.f);
            V.x = fmaxf(V.x * sO, sl[j].x);
            V.y = fmaxf(V.y * sO, sl[j].y);
            V.z = fmaxf(V.z * sO, sl[j].z);
            V.w = fmaxf(V.w * sO, sl[j].w);
            M = p;
          }
        }
      }
    }
    cl = cln;
  }
  float inv = 1.0f / D;
  float4 b = *(const float4*)&bias[l4];
  float4 o;
  o.x = fmaxf(V.x * inv + b.x, 0.f);
  o.y = fmaxf(V.y * inv + b.y, 0.f);
  o.z = fmaxf(V.z * inv + b.z, 0.f);
  o.w = fmaxf(V.w * inv + b.w, 0.f);
  if (!HEAD) {
    *(float4*)&h[n * DH + l4] = o;
  } else {
    // out[n] = relu(o @ W3 + b3) @ W4 + b4 ; lane l owns dims j = l4..l4+3
    float4 acc = {0.f, 0.f, 0.f, 0.f};
    #pragma unroll
    for (int kk = 0; kk < 16; kk++) {
      float4 hk;
      hk.x = __shfl(o.x, g0 + kk);
      hk.y = __shfl(o.y, g0 + kk);
      hk.z = __shfl(o.z, g0 + kk);
      hk.w = __shfl(o.w, g0 + kk);
      float4 w0 = *(const float4*)&W3[(kk * 4 + 0) * DH + l4];
      acc.x = fmaf(hk.x, w0.x, acc.x);
      acc.y = fmaf(hk.x, w0.y, acc.y);
      acc.z = fmaf(hk.x, w0.z, acc.z);
      acc.w = fmaf(hk.x, w0.w, acc.w);
      float4 w1 = *(const float4*)&W3[(kk * 4 + 1) * DH + l4];
      acc.x = fmaf(hk.y, w1.x, acc.x);
      acc.y = fmaf(hk.y, w1.y, acc.y);
      acc.z = fmaf(hk.y, w1.z, acc.z);
      acc.w = fmaf(hk.y, w1.w, acc.w);
      float4 w2 = *(const float4*)&W3[(kk * 4 + 2) * DH + l4];
      acc.x = fmaf(hk.z, w2.x, acc.x);
      acc.y = fmaf(hk.z, w2.y, acc.y);
      acc.z = fmaf(hk.z, w2.z, acc.z);
      acc.w = fmaf(hk.z, w2.w, acc.w);
      float4 w3 = *(const float4*)&W3[(kk * 4 + 3) * DH + l4];
      acc.x = fmaf(hk.w, w3.x, acc.x);
      acc.y = fmaf(hk.w, w3.y, acc.y);
      acc.z = fmaf(hk.w, w3.z, acc.z);
      acc.w = fmaf(hk.w, w3.w, acc.w);
    }
    float4 b3v = *(const float4*)&b3[l4];
    float4 w4v = *(const float4*)&W4[l4];
    float t, p = 0.f;
    t = acc.x + b3v.x; t = t > 0.f ? t : 0.f; p += t * w4v.x;
    t = acc.y + b3v.y; t = t > 0.f ? t : 0.f; p += t * w4v.y;
    t = acc.z + b3v.z; t = t > 0.f ? t : 0.f; p += t * w4v.z;
    t = acc.w + b3v.w; t = t > 0.f ? t : 0.f; p += t * w4v.w;
    p += __shfl_xor(p, 1);
    p += __shfl_xor(p, 2);
    p += __shfl_xor(p, 4);
    p += __shfl_xor(p, 8);
    if (l == 0) out[n] = p + b4[0];
  }
}

extern "C" void kernel_launch(void* const* d_in, const int* in_sizes, int n_in,
                              void* d_out, int out_size, void* d_ws, size_t ws_size,
                              hipStream_t stream) {
  const float* x      = (const float*)d_in[0];
  const int*   ei     = (const int*)d_in[1];
  const float* ea     = (const float*)d_in[2];
  const float* l1_Wl  = (const float*)d_in[3];
  const float* l1_bl  = (const float*)d_in[4];
  const float* l1_Wr  = (const float*)d_in[5];
  const float* l1_br  = (const float*)d_in[6];
  const float* l1_We  = (const float*)d_in[7];
  const float* l1_att = (const float*)d_in[8];
  const float* l1_bias= (const float*)d_in[9];
  const float* l2_Wl  = (const float*)d_in[10];
  const float* l2_bl  = (const float*)d_in[11];
  const float* l2_Wr  = (const float*)d_in[12];
  const float* l2_br  = (const float*)d_in[13];
  const float* l2_We  = (const float*)d_in[14];
  const float* l2_att = (const float*)d_in[15];
  const float* l2_bias= (const float*)d_in[16];
  const float* W3     = (const float*)d_in[17];
  const float* b3     = (const float*)d_in[18];
  const float* W4     = (const float*)d_in[19];
  const float* b4     = (const float*)d_in[20];
  float* out = (float*)d_out;

  float*    ws     = (float*)d_ws;
  float*    sum    = ws;                        // 256 floats (only [0] used)
  float*    xl     = ws + 256;                  // NN*DH
  float*    xr     = xl + NN * DH;              // NN*DH
  float*    h      = xr + NN * DH;              // NN*DH
  int2*     csr    = (int2*)(h + NN * DH);      // ETOT int2 (8B aligned)
  unsigned* rowptr = (unsigned*)(csr + ETOT);   // NN+1 (+3 pad for alignment)
  unsigned* wptr   = rowptr + NN + 4;           // NN   (16B aligned)
  unsigned* deg    = wptr + NN;                 // NN   (16B aligned)
  unsigned* bsum   = deg + NN;                  // NB, padded to 128 uints
  unsigned short* wf1h = (unsigned short*)(bsum + 128);  // 8*9*64*8 = 36864
  unsigned short* wf1l = wf1h + 36864;
  unsigned short* wf2h = wf1l + 36864;          // 8*2*64*8 = 8192
  unsigned short* wf2l = wf2h + 8192;

  const int B = 256;
  const int mm_blocks   = (NN + 63) / 64;                 // 1563 (64 rows/block)
  const int shard_blocks = NSHARD * ((ETOT + EPB - 1) / EPB);  // 8 * 831 = 6648
  const int attn_blocks = (NN * 16) / B;                  // 6250

  // ---- graph preprocessing + weight repack (independent of each other) ----
  hipMemsetAsync(sum, 0, 256 * sizeof(float), stream);
  hipMemsetAsync(deg, 0, NN * sizeof(unsigned), stream);
  k_wprep<DIN><<<(8 * 9 * 64 + B - 1) / B, B, 0, stream>>>(l1_Wl, l1_Wr, wf1h, wf1l);
  k_wprep<DH><<<(8 * 2 * 64 + B - 1) / B, B, 0, stream>>>(l2_Wl, l2_Wr, wf2h, wf2l);
  k_mean<<<1024, B, 0, stream>>>(ea, sum);
  k_hist<<<shard_blocks, B, 0, stream>>>(ei, deg);
  k_bsum<<<NB, B, 0, stream>>>(deg, bsum);
  k_sscan<<<1, 128, 0, stream>>>(bsum, rowptr);
  k_scan2<<<NB, B, 0, stream>>>(deg, bsum, rowptr, wptr);
  k_scatter<<<shard_blocks, B, 0, stream>>>(ei, ea, sum, wptr, csr);

  // ---- layer 1 ----
  k_mm<DIN><<<mm_blocks, 512, 0, stream>>>(x, wf1h, wf1l, l1_bl, l1_br, xl, xr);
  k_attn<false><<<attn_blocks, B, 0, stream>>>(rowptr, csr, xl, xr, l1_We, l1_att,
                                               l1_bias, h, W3, b3, W4, b4, out);

  // ---- layer 2 + head (fused) ----
  k_mm<DH><<<mm_blocks, 512, 0, stream>>>(h, wf2h, wf2l, l2_bl, l2_br, xl, xr);
  k_attn<true><<<attn_blocks, B, 0, stream>>>(rowptr, csr, xl, xr, l2_We, l2_att,
                                              l2_bias, h, W3, b3, W4, b4, out);
}

// Round 8
// 623.773 us; speedup vs baseline: 1.0830x; 1.0830x over previous
//
#include <hip/hip_runtime.h>
#include <math.h>
#include <float.h>

#define NN 100000
#define NE 1600000
#define ETOT 1700000   // NE + NN self loops
#define DIN 264
#define DH 64
#define SLOPE 0.2f
#define NB 98          // scan blocks: ceil(NN/1024)
#define NSHARD 8       // one dst-range shard per XCD
#define SHW 12500      // NN / NSHARD
#define EPB 2048       // edges per block-chunk in sharded edge kernels

typedef __attribute__((ext_vector_type(8))) short s8v;   // 8 bf16 = 4 VGPR
typedef __attribute__((ext_vector_type(4))) float f4v;   // MFMA acc

__device__ __forceinline__ unsigned short f2bf(float x) {  // rne f32->bf16
  unsigned u = __float_as_uint(x);
  u += 0x7FFFu + ((u >> 16) & 1u);
  return (unsigned short)(u >> 16);
}
__device__ __forceinline__ float bf2f(unsigned short h) {
  return __uint_as_float(((unsigned)h) << 16);
}

__global__ void k_mean(const float* __restrict__ ea, float* __restrict__ sum) {
  float acc = 0.f;
  for (int i = blockIdx.x * blockDim.x + threadIdx.x; i < NE; i += gridDim.x * blockDim.x)
    acc += ea[i];
  #pragma unroll
  for (int off = 32; off > 0; off >>= 1) acc += __shfl_xor(acc, off);
  __shared__ float s[4];
  int lane = threadIdx.x & 63, w = threadIdx.x >> 6;
  if (lane == 0) s[w] = acc;
  __syncthreads();
  if (threadIdx.x == 0) atomicAdd(sum, s[0] + s[1] + s[2] + s[3]);
}

// XCD-sharded histogram: blocks with blockIdx%8==b own dst range
// [b*SHW,(b+1)*SHW).  Round-robin block->XCD dispatch (perf heuristic,
// correctness shard-exhaustive) keeps each deg/csr line dirty on ONE XCD.
__global__ __launch_bounds__(256)
void k_hist(const int* __restrict__ ei, unsigned* __restrict__ deg) {
  const int shard = blockIdx.x & (NSHARD - 1);
  const int g = blockIdx.x >> 3;
  const int dlo = shard * SHW, dhi = dlo + SHW;
  int e0 = g * EPB + threadIdx.x;
  #pragma unroll
  for (int k = 0; k < EPB / 256; k++) {
    int e = e0 + k * 256;
    if (e < ETOT) {
      int d = (e < NE) ? ei[NE + e] : e - NE;
      if (d >= dlo && d < dhi) atomicAdd(&deg[d], 1u);
    }
  }
}

// ---- parallel 3-phase scan ----
__global__ __launch_bounds__(256)
void k_bsum(const unsigned* __restrict__ deg, unsigned* __restrict__ bsum) {
  int i0 = blockIdx.x * 1024 + threadIdx.x * 4;
  unsigned s = 0;
  if (i0 + 3 < NN) {
    uint4 v = *(const uint4*)&deg[i0];
    s = v.x + v.y + v.z + v.w;
  }
  #pragma unroll
  for (int off = 32; off > 0; off >>= 1) s += __shfl_xor(s, off);
  __shared__ unsigned ws[4];
  int lane = threadIdx.x & 63, w = threadIdx.x >> 6;
  if (lane == 0) ws[w] = s;
  __syncthreads();
  if (threadIdx.x == 0) bsum[blockIdx.x] = ws[0] + ws[1] + ws[2] + ws[3];
}

__global__ __launch_bounds__(128)
void k_sscan(unsigned* __restrict__ bsum, unsigned* __restrict__ rowptr) {
  __shared__ unsigned ls[128];
  int t = threadIdx.x;
  unsigned v = (t < NB) ? bsum[t] : 0u;
  ls[t] = v;
  __syncthreads();
  for (int off = 1; off < 128; off <<= 1) {
    unsigned u = (t >= off) ? ls[t - off] : 0u;
    __syncthreads();
    ls[t] += u;
    __syncthreads();
  }
  if (t < NB) bsum[t] = ls[t] - v;  // exclusive
  if (t == 127) rowptr[NN] = ls[127];
}

__global__ __launch_bounds__(256)
void k_scan2(const unsigned* __restrict__ deg, const unsigned* __restrict__ bsum,
             unsigned* __restrict__ rowptr, unsigned* __restrict__ wptr) {
  __shared__ unsigned ls[256];
  int i0 = blockIdx.x * 1024 + threadIdx.x * 4;
  unsigned d0 = 0, d1 = 0, d2 = 0, d3 = 0;
  if (i0 + 3 < NN) {
    uint4 v = *(const uint4*)&deg[i0];
    d0 = v.x; d1 = v.y; d2 = v.z; d3 = v.w;
  }
  unsigned ts = d0 + d1 + d2 + d3;
  ls[threadIdx.x] = ts;
  __syncthreads();
  for (int off = 1; off < 256; off <<= 1) {
    unsigned u = (threadIdx.x >= (unsigned)off) ? ls[threadIdx.x - off] : 0u;
    __syncthreads();
    ls[threadIdx.x] += u;
    __syncthreads();
  }
  unsigned base = bsum[blockIdx.x] + ls[threadIdx.x] - ts;  // exclusive
  if (i0 + 3 < NN) {
    uint4 r;
    r.x = base;
    r.y = base + d0;
    r.z = r.y + d1;
    r.w = r.z + d2;
    *(uint4*)&rowptr[i0] = r;
    *(uint4*)&wptr[i0] = r;
  }
}

// XCD-sharded CSR scatter (see k_hist comment).
__global__ __launch_bounds__(256)
void k_scatter(const int* __restrict__ ei, const float* __restrict__ ea,
               const float* __restrict__ sump, unsigned* __restrict__ wptr,
               int2* __restrict__ csr) {
  const int shard = blockIdx.x & (NSHARD - 1);
  const int g = blockIdx.x >> 3;
  const int dlo = shard * SHW, dhi = dlo + SHW;
  int e0 = g * EPB + threadIdx.x;
  #pragma unroll
  for (int k = 0; k < EPB / 256; k++) {
    int e = e0 + k * 256;
    if (e >= ETOT) continue;
    int d = (e < NE) ? ei[NE + e] : e - NE;
    if (d < dlo || d >= dhi) continue;
    int s;
    float a;
    if (e < NE) {
      s = ei[e];
      a = ea[e];
    } else {
      s = d;
      a = sump[0] * (1.0f / NE);
    }
    unsigned pos = atomicAdd(&wptr[d], 1u);
    csr[pos] = make_int2(s, __float_as_int(a));
  }
}

// Repack Wl|Wr (K x 64 row-major fp32) into MFMA B-fragment order, split
// bf16 hi/lo.  8 n-tiles total (0-3 -> Wl, 4-7 -> Wr); per fragment, lane l
// supplies B[k = kc*32 + 8*(l>>4) + i][n = nt*16 + (l&15)] (zero-pad k >= K).
template <int K>
__global__ __launch_bounds__(256)
void k_wprep(const float* __restrict__ Wl, const float* __restrict__ Wr,
             unsigned short* __restrict__ wfh, unsigned short* __restrict__ wfl) {
  constexpr int KC = (K + 31) / 32;
  int t = blockIdx.x * blockDim.x + threadIdx.x;  // one thread per fragment-lane
  if (t >= 8 * KC * 64) return;
  int lane = t & 63;
  int kc = (t >> 6) % KC;
  int ntg = t / (64 * KC);
  const float* src = (ntg < 4) ? Wl : Wr;
  int n = (ntg & 3) * 16 + (lane & 15);
  int k0 = kc * 32 + (lane >> 4) * 8;
  #pragma unroll
  for (int i = 0; i < 8; i++) {
    int k = k0 + i;
    float v = (k < K) ? src[k * DH + n] : 0.f;
    unsigned short hh = f2bf(v);
    wfh[t * 8 + i] = hh;
    wfl[t * 8 + i] = f2bf(v - bf2f(hh));
  }
}

// MFMA GEMM: [xl xr] = X @ [Wl Wr] + [bl br] via split-bf16
// (Xh*Wh + Xh*Wlo + Xlo*Wh; dropped lo*lo term <= 2^-16 relative).
// 512 threads = 8 waves per 64-row block; wave w owns ONE n-tile
// (w<4 -> xl cols, w>=4 -> xr cols), all 4 m-tiles.  Wave's ENTIRE B set
// preloaded to registers before staging; K-loop is LDS+MFMA only.
template <int K>
__global__ __launch_bounds__(512) __attribute__((amdgpu_waves_per_eu(4)))
void k_mm(const float* __restrict__ X,
          const unsigned short* __restrict__ wfh, const unsigned short* __restrict__ wfl,
          const float* __restrict__ bl, const float* __restrict__ br,
          float* __restrict__ xl, float* __restrict__ xr) {
  constexpr int KC = (K + 31) / 32;
  constexpr int KP = KC * 32;
  constexpr int SP = KP + 8;  // +8 shorts: bank-spread for the A-frag reads
  __shared__ unsigned short lsh[64 * SP];
  __shared__ unsigned short lsl[64 * SP];
  const int r0 = blockIdx.x * 64;
  const int tid = threadIdx.x;
  const int lane = tid & 63, w = tid >> 6;
  const int kq = lane >> 4;   // k-octet / C-row group
  const int ar = lane & 15;   // A row within tile / C col

  // ---- preload this wave's B fragments (n-tile = w) for all kc ----
  s8v bh[KC], bv[KC];
  #pragma unroll
  for (int kc = 0; kc < KC; kc++) {
    const int bidx = ((w * KC + kc) * 64 + lane) * 8;
    bh[kc] = *(const s8v*)&wfh[bidx];
    bv[kc] = *(const s8v*)&wfl[bidx];
  }

  // ---- stage X -> LDS bf16 hi/lo (coalesced float2 loads) ----
  if constexpr (KP > K) {  // zero the k-pad strip [K, KP)
    constexpr int PADW = (KP - K) / 2;  // uints per row
    for (int t = tid; t < 64 * PADW; t += 512) {
      int row = t / PADW, c = t - row * PADW;
      *(unsigned*)&lsh[row * SP + K + 2 * c] = 0u;
      *(unsigned*)&lsl[row * SP + K + 2 * c] = 0u;
    }
  }
  {
    constexpr int HK = K / 2;
    for (int p = tid; p < 64 * HK; p += 512) {
      int row = p / HK, kp = p - row * HK;
      int grow = r0 + row;
      float a = 0.f, b = 0.f;
      if (grow < NN) {
        float2 v = *(const float2*)&X[(size_t)grow * K + 2 * kp];
        a = v.x; b = v.y;
      }
      unsigned short ha = f2bf(a), hb = f2bf(b);
      unsigned short la = f2bf(a - bf2f(ha)), lb = f2bf(b - bf2f(hb));
      *(unsigned*)&lsh[row * SP + 2 * kp] = (unsigned)ha | ((unsigned)hb << 16);
      *(unsigned*)&lsl[row * SP + 2 * kp] = (unsigned)la | ((unsigned)lb << 16);
    }
  }
  __syncthreads();

  // ---- K-loop: LDS reads + MFMA only ----
  f4v acc[4];
  #pragma unroll
  for (int mt = 0; mt < 4; mt++) acc[mt] = (f4v){0.f, 0.f, 0.f, 0.f};
  #pragma unroll
  for (int kc = 0; kc < KC; kc++) {
    const int kb = kc * 32 + kq * 8;
    #pragma unroll
    for (int mt = 0; mt < 4; mt++) {
      s8v ah = *(const s8v*)&lsh[(mt * 16 + ar) * SP + kb];
      s8v al = *(const s8v*)&lsl[(mt * 16 + ar) * SP + kb];
      acc[mt] = __builtin_amdgcn_mfma_f32_16x16x32_bf16(ah, bh[kc], acc[mt], 0, 0, 0);
      acc[mt] = __builtin_amdgcn_mfma_f32_16x16x32_bf16(ah, bv[kc], acc[mt], 0, 0, 0);
      acc[mt] = __builtin_amdgcn_mfma_f32_16x16x32_bf16(al, bh[kc], acc[mt], 0, 0, 0);
    }
  }

  // C/D layout (m89-verified): col = lane&15, row = (lane>>4)*4 + reg
  const float* bias = (w < 4) ? bl : br;
  float* outp = (w < 4) ? xl : xr;
  const int col = (w & 3) * 16 + ar;
  const float bvv = bias[col];
  #pragma unroll
  for (int mt = 0; mt < 4; mt++) {
    #pragma unroll
    for (int r = 0; r < 4; r++) {
      int grow = r0 + mt * 16 + kq * 4 + r;
      if (grow < NN) outp[(size_t)grow * DH + col] = acc[mt][r] + bvv;
    }
  }
}

// Fused per-node attention: 16 lanes own one dst node; online softmax + max-aggregate.
// Round-8: round-6 structure restored (4-deep gather batches, no prefetch --
// round-7's 8-deep + prefetch grew VGPR 36->56, occupancy 61->36%, dur +30%).
// Only surviving change: BRANCHLESS single-exp online update.  d=p-M,
// e=exp(-|d|); sN=(d<=0)?e:1, sO=(d<=0)?1:e.  Bit-exact vs two-exp form
// (exp(0)=1; x*1.0 and fma(D,1,sN) exact), saves one transcendental/edge,
// costs 2 cndmask, zero extra registers.
template <bool HEAD>
__global__ void k_attn(const unsigned* __restrict__ rowptr, const int2* __restrict__ csr,
                       const float* __restrict__ xl, const float* __restrict__ xr,
                       const float* __restrict__ We, const float* __restrict__ att,
                       const float* __restrict__ bias, float* __restrict__ h,
                       const float* __restrict__ W3, const float* __restrict__ b3,
                       const float* __restrict__ W4, const float* __restrict__ b4,
                       float* __restrict__ out) {
  int n = (blockIdx.x * blockDim.x + threadIdx.x) >> 4;
  int l = threadIdx.x & 15;
  int g0 = threadIdx.x & 48;  // 16-lane group base within the wave
  if (n >= NN) return;        // exact division: never taken, no partial groups
  int l4 = l * 4;
  float4 xr4 = *(const float4*)&xr[n * DH + l4];
  float4 we4 = *(const float4*)&We[l4];
  float4 at4 = *(const float4*)&att[l4];
  int beg = rowptr[n], end = rowptr[n + 1];  // deg >= 1 (self loop)
  float M, D;
  float4 V;
  {  // peel first edge
    int2 c0 = csr[beg];
    float a = __int_as_float(c0.y);
    float4 sl = *(const float4*)&xl[c0.x * DH + l4];
    float v, p = 0.f;
    v = xr4.x + sl.x + a * we4.x; v = fmaxf(v, SLOPE * v); p += v * at4.x;
    v = xr4.y + sl.y + a * we4.y; v = fmaxf(v, SLOPE * v); p += v * at4.y;
    v = xr4.z + sl.z + a * we4.z; v = fmaxf(v, SLOPE * v); p += v * at4.z;
    v = xr4.w + sl.w + a * we4.w; v = fmaxf(v, SLOPE * v); p += v * at4.w;
    p += __shfl_xor(p, 1);
    p += __shfl_xor(p, 2);
    p += __shfl_xor(p, 4);
    p += __shfl_xor(p, 8);
    M = p; D = 1.f; V = sl;
  }
  for (int e0 = beg + 1; e0 < end; e0 += 16) {
    int2 cl = csr[min(e0 + l, end - 1)];  // coalesced 128B per group
    int cnt = min(16, end - e0);
    for (int i = 0; i < cnt; i += 4) {
      int mm = min(4, cnt - i);
      float4 sl[4];
      float av[4];
      #pragma unroll
      for (int j = 0; j < 4; j++) {
        if (j < mm) {
          int s = __shfl(cl.x, g0 + i + j);
          av[j] = __int_as_float(__shfl(cl.y, g0 + i + j));
          sl[j] = *(const float4*)&xl[s * DH + l4];  // 4 gathers in flight
        }
      }
      #pragma unroll
      for (int j = 0; j < 4; j++) {
        if (j < mm) {
          float a = av[j];
          float v, p = 0.f;
          v = xr4.x + sl[j].x + a * we4.x; v = fmaxf(v, SLOPE * v); p += v * at4.x;
          v = xr4.y + sl[j].y + a * we4.y; v = fmaxf(v, SLOPE * v); p += v * at4.y;
          v = xr4.z + sl[j].z + a * we4.z; v = fmaxf(v, SLOPE * v); p += v * at4.z;
          v = xr4.w + sl[j].w + a * we4.w; v = fmaxf(v, SLOPE * v); p += v * at4.w;
          p += __shfl_xor(p, 1);
          p += __shfl_xor(p, 2);
          p += __shfl_xor(p, 4);
          p += __shfl_xor(p, 8);
          float d = p - M;
          float e = __expf(-fabsf(d));
          float sN = (d <= 0.f) ? e : 1.f;
          float sO = (d <= 0.f) ? 1.f : e;
          M = fmaxf(M, p);
          D = fmaf(D, sO, sN);
          V.x = fmaxf(V.x * sO, sl[j].x * sN);
          V.y = fmaxf(V.y * sO, sl[j].y * sN);
          V.z = fmaxf(V.z * sO, sl[j].z * sN);
          V.w = fmaxf(V.w * sO, sl[j].w * sN);
        }
      }
    }
  }
  float inv = 1.0f / D;
  float4 b = *(const float4*)&bias[l4];
  float4 o;
  o.x = fmaxf(V.x * inv + b.x, 0.f);
  o.y = fmaxf(V.y * inv + b.y, 0.f);
  o.z = fmaxf(V.z * inv + b.z, 0.f);
  o.w = fmaxf(V.w * inv + b.w, 0.f);
  if (!HEAD) {
    *(float4*)&h[n * DH + l4] = o;
  } else {
    // out[n] = relu(o @ W3 + b3) @ W4 + b4 ; lane l owns dims j = l4..l4+3
    float4 acc = {0.f, 0.f, 0.f, 0.f};
    #pragma unroll
    for (int kk = 0; kk < 16; kk++) {
      float4 hk;
      hk.x = __shfl(o.x, g0 + kk);
      hk.y = __shfl(o.y, g0 + kk);
      hk.z = __shfl(o.z, g0 + kk);
      hk.w = __shfl(o.w, g0 + kk);
      float4 w0 = *(const float4*)&W3[(kk * 4 + 0) * DH + l4];
      acc.x = fmaf(hk.x, w0.x, acc.x);
      acc.y = fmaf(hk.x, w0.y, acc.y);
      acc.z = fmaf(hk.x, w0.z, acc.z);
      acc.w = fmaf(hk.x, w0.w, acc.w);
      float4 w1 = *(const float4*)&W3[(kk * 4 + 1) * DH + l4];
      acc.x = fmaf(hk.y, w1.x, acc.x);
      acc.y = fmaf(hk.y, w1.y, acc.y);
      acc.z = fmaf(hk.y, w1.z, acc.z);
      acc.w = fmaf(hk.y, w1.w, acc.w);
      float4 w2 = *(const float4*)&W3[(kk * 4 + 2) * DH + l4];
      acc.x = fmaf(hk.z, w2.x, acc.x);
      acc.y = fmaf(hk.z, w2.y, acc.y);
      acc.z = fmaf(hk.z, w2.z, acc.z);
      acc.w = fmaf(hk.z, w2.w, acc.w);
      float4 w3 = *(const float4*)&W3[(kk * 4 + 3) * DH + l4];
      acc.x = fmaf(hk.w, w3.x, acc.x);
      acc.y = fmaf(hk.w, w3.y, acc.y);
      acc.z = fmaf(hk.w, w3.z, acc.z);
      acc.w = fmaf(hk.w, w3.w, acc.w);
    }
    float4 b3v = *(const float4*)&b3[l4];
    float4 w4v = *(const float4*)&W4[l4];
    float t, p = 0.f;
    t = acc.x + b3v.x; t = t > 0.f ? t : 0.f; p += t * w4v.x;
    t = acc.y + b3v.y; t = t > 0.f ? t : 0.f; p += t * w4v.y;
    t = acc.z + b3v.z; t = t > 0.f ? t : 0.f; p += t * w4v.z;
    t = acc.w + b3v.w; t = t > 0.f ? t : 0.f; p += t * w4v.w;
    p += __shfl_xor(p, 1);
    p += __shfl_xor(p, 2);
    p += __shfl_xor(p, 4);
    p += __shfl_xor(p, 8);
    if (l == 0) out[n] = p + b4[0];
  }
}

extern "C" void kernel_launch(void* const* d_in, const int* in_sizes, int n_in,
                              void* d_out, int out_size, void* d_ws, size_t ws_size,
                              hipStream_t stream) {
  const float* x      = (const float*)d_in[0];
  const int*   ei     = (const int*)d_in[1];
  const float* ea     = (const float*)d_in[2];
  const float* l1_Wl  = (const float*)d_in[3];
  const float* l1_bl  = (const float*)d_in[4];
  const float* l1_Wr  = (const float*)d_in[5];
  const float* l1_br  = (const float*)d_in[6];
  const float* l1_We  = (const float*)d_in[7];
  const float* l1_att = (const float*)d_in[8];
  const float* l1_bias= (const float*)d_in[9];
  const float* l2_Wl  = (const float*)d_in[10];
  const float* l2_bl  = (const float*)d_in[11];
  const float* l2_Wr  = (const float*)d_in[12];
  const float* l2_br  = (const float*)d_in[13];
  const float* l2_We  = (const float*)d_in[14];
  const float* l2_att = (const float*)d_in[15];
  const float* l2_bias= (const float*)d_in[16];
  const float* W3     = (const float*)d_in[17];
  const float* b3     = (const float*)d_in[18];
  const float* W4     = (const float*)d_in[19];
  const float* b4     = (const float*)d_in[20];
  float* out = (float*)d_out;

  float*    ws     = (float*)d_ws;
  float*    sum    = ws;                        // 256 floats (only [0] used)
  float*    xl     = ws + 256;                  // NN*DH
  float*    xr     = xl + NN * DH;              // NN*DH
  float*    h      = xr + NN * DH;              // NN*DH
  int2*     csr    = (int2*)(h + NN * DH);      // ETOT int2 (8B aligned)
  unsigned* rowptr = (unsigned*)(csr + ETOT);   // NN+1 (+3 pad for alignment)
  unsigned* wptr   = rowptr + NN + 4;           // NN   (16B aligned)
  unsigned* deg    = wptr + NN;                 // NN   (16B aligned)
  unsigned* bsum   = deg + NN;                  // NB, padded to 128 uints
  unsigned short* wf1h = (unsigned short*)(bsum + 128);  // 8*9*64*8 = 36864
  unsigned short* wf1l = wf1h + 36864;
  unsigned short* wf2h = wf1l + 36864;          // 8*2*64*8 = 8192
  unsigned short* wf2l = wf2h + 8192;

  const int B = 256;
  const int mm_blocks   = (NN + 63) / 64;                 // 1563 (64 rows/block)
  const int shard_blocks = NSHARD * ((ETOT + EPB - 1) / EPB);  // 8 * 831 = 6648
  const int attn_blocks = (NN * 16) / B;                  // 6250

  // ---- graph preprocessing + weight repack (independent of each other) ----
  hipMemsetAsync(sum, 0, 256 * sizeof(float), stream);
  hipMemsetAsync(deg, 0, NN * sizeof(unsigned), stream);
  k_wprep<DIN><<<(8 * 9 * 64 + B - 1) / B, B, 0, stream>>>(l1_Wl, l1_Wr, wf1h, wf1l);
  k_wprep<DH><<<(8 * 2 * 64 + B - 1) / B, B, 0, stream>>>(l2_Wl, l2_Wr, wf2h, wf2l);
  k_mean<<<1024, B, 0, stream>>>(ea, sum);
  k_hist<<<shard_blocks, B, 0, stream>>>(ei, deg);
  k_bsum<<<NB, B, 0, stream>>>(deg, bsum);
  k_sscan<<<1, 128, 0, stream>>>(bsum, rowptr);
  k_scan2<<<NB, B, 0, stream>>>(deg, bsum, rowptr, wptr);
  k_scatter<<<shard_blocks, B, 0, stream>>>(ei, ea, sum, wptr, csr);

  // ---- layer 1 ----
  k_mm<DIN><<<mm_blocks, 512, 0, stream>>>(x, wf1h, wf1l, l1_bl, l1_br, xl, xr);
  k_attn<false><<<attn_blocks, B, 0, stream>>>(rowptr, csr, xl, xr, l1_We, l1_att,
                                               l1_bias, h, W3, b3, W4, b4, out);

  // ---- layer 2 + head (fused) ----
  k_mm<DH><<<mm_blocks, 512, 0, stream>>>(h, wf2h, wf2l, l2_bl, l2_br, xl, xr);
  k_attn<true><<<attn_blocks, B, 0, stream>>>(rowptr, csr, xl, xr, l2_We, l2_att,
                                              l2_bias, h, W3, b3, W4, b4, out);
}